// Round 5
// baseline (291.575 us; speedup 1.0000x reference)
//
#include <hip/hip_runtime.h>

// x: [16,128,128,128] fp32 ; pixel_shuffle(2) -> [16,32,256,256]
// 4x4 separable FIR (outer([1,3,3,1])/64), pad=2 -> out [16,32,257,257]
//
// R7: barrier-free, LDS-free, one wave = one full output row-strip.
// R5/R6 post-mortem: LDS-staged design plateaued at 91us with VALU 18%,
// DS ~30%, HBM 36% — no pipe saturated; the cost was the structure itself
// (68 barriers/block, 4-wave lockstep, ds_write->barrier->ds_read 120cy
// chain per 1KB of output). Two structural probes (prefetch ring depth,
// lgkm-only barrier) both returned zero => delete the round-trip.
// New: lane owns 4 consecutive out cols (c=4*lane..+3). Per shuffled row,
// lane loads float2 from even plane (E[2m],E[2m+1]) + float2 from odd
// plane (O[2m],O[2m+1]) — 512B/wave-instr, coalesced, 8B-aligned. The
// 4-col horizontal FIR needs only E[2m-1],O[2m-1] (shfl_up 1) and
// E[2m+2] (shfl_down 1): 3 conflict-free ds_bpermute, wave edges are the
// global zero-pad (lane0/lane63 cndmask). Col 256 = h0*E[127]+h1*O[127]
// = lane63's own values. Vertical 4-tap: rolling registers, unrolled.
// 512 bc x 16 strips(17 rows) = 8192 waves = exactly 32/CU, independent.
// Double-buffered row prefetch (2 ahead) in registers; nothing drains it.
// Invariant: VGPR <= 64 (8 waves/SIMD).
constexpr int Hn = 128;
constexpr int Wn = 128;
constexpr int SH = 2 * Hn;   // 256 shuffled rows
constexpr int OH = SH + 1;   // 257
constexpr int OW = 257;
constexpr int HW = Hn * Wn;  // input plane stride
constexpr int TY = 17;       // output rows per wave
constexpr int NSTRIP = 16;   // 16*17 = 272 >= 257
constexpr int NBC = 16 * 32; // 512 (b,c) planes
constexpr int NIT = TY + 3;  // 20 staged shuffled rows per strip

__global__ __launch_bounds__(256, 8) void upsamp_fir_wave(
    const float* __restrict__ x,
    const float* __restrict__ k4,
    float* __restrict__ out)
{
    const int tix   = threadIdx.x;
    const int lane  = tix & 63;
    const int wid   = tix >> 6;
    const int bc    = blockIdx.x;
    const int strip = blockIdx.y * 4 + wid;
    const int oh0   = strip * TY;

    const float* xp = x + (size_t)bc * 4 * HW;

    // Separable taps (flipped for true convolution), exact for this kernel.
    float fh[4], fv[4];
#pragma unroll
    for (int j = 0; j < 4; ++j) fh[j] = k4[j] + k4[4+j] + k4[8+j] + k4[12+j];
#pragma unroll
    for (int i = 0; i < 4; ++i) fv[i] = k4[4*i] + k4[4*i+1] + k4[4*i+2] + k4[4*i+3];
    const float h0 = fh[3], h1 = fh[2], h2 = fh[1], h3 = fh[0];
    const float g0 = fv[3], g1 = fv[2], g2 = fv[1], g3 = fv[0];

    const bool l0  = (lane == 0);
    const bool l63 = (lane == 63);
    const int  colOff = 2 * lane;              // input col of E2.x / O2.x

    // Load shuffled row s: E pair (even cols 4m,4m+2 -> input cols 2m,2m+1
    // of plane 2*(s&1)) and O pair (odd cols, plane 2*(s&1)+1).
    auto loadrow = [&](int s, float2& e2, float2& o2) {
        if ((unsigned)s >= (unsigned)SH) {
            e2 = make_float2(0.f, 0.f); o2 = e2; return;
        }
        const float* be = xp + (size_t)((s & 1) * 2) * HW
                             + (size_t)(s >> 1) * Wn + colOff;
        e2 = *(const float2*)be;
        o2 = *(const float2*)(be + HW);
    };

    float2 eA, oA, eB, oB;
    loadrow(oh0 - 2, eA, oA);
    loadrow(oh0 - 1, eB, oB);

    // Rolling horizontal results for the 4 owned cols + edge col 256.
    float m30=0,m31=0,m32=0,m33=0;   // H(s-3)
    float m20=0,m21=0,m22=0,m23=0;   // H(s-2)
    float m10=0,m11=0,m12=0,m13=0;   // H(s-1)
    float e3=0, e2r=0, e1r=0;        // edge col rolling

    float* const obase = out + (size_t)bc * OH * OW;

    auto step = [&](int i, float2& E2, float2& O2) {
        const int s = oh0 - 2 + i;
        const float Ex = E2.x, Ey = E2.y, Ox = O2.x, Oy = O2.y;
        // Cross-lane neighbors (wave edge = global zero-pad).
        float Em1 = __shfl_up(Ey, 1);   Em1 = l0  ? 0.f : Em1;  // E[2m-1]
        float Om1 = __shfl_up(Oy, 1);   Om1 = l0  ? 0.f : Om1;  // O[2m-1]
        float Ep1 = __shfl_down(Ex, 1); Ep1 = l63 ? 0.f : Ep1;  // E[2m+2]
        // Horizontal FIR, out cols 4m..4m+3 (+ col 256 in lane 63).
        const float H0 = h0*Em1 + h1*Om1 + h2*Ex + h3*Ox;
        const float H1 = h0*Om1 + h1*Ex  + h2*Ox + h3*Ey;
        const float H2 = h0*Ex  + h1*Ox  + h2*Ey + h3*Oy;
        const float H3 = h0*Ox  + h1*Ey  + h2*Oy + h3*Ep1;
        const float H4 = h0*Ey  + h1*Oy;                    // col 256
        // Prefetch row s+2 into this buffer (consumed 2 steps later).
        if (i + 2 < NIT) loadrow(s + 2, E2, O2);
        // Emit output row oh = s-1 (needs H rows s-3..s).
        if (i >= 3) {
            const int oh = oh0 + i - 3;
            if (oh < OH) {
                float* pr = obase + (size_t)oh * OW + 4 * lane;
                pr[0] = g0*m30 + g1*m20 + g2*m10 + g3*H0;
                pr[1] = g0*m31 + g1*m21 + g2*m11 + g3*H1;
                pr[2] = g0*m32 + g1*m22 + g2*m12 + g3*H2;
                pr[3] = g0*m33 + g1*m23 + g2*m13 + g3*H3;
                if (l63) pr[4] = g0*e3 + g1*e2r + g2*e1r + g3*H4; // col 256
            }
        }
        // Roll.
        m30=m20; m31=m21; m32=m22; m33=m23;
        m20=m10; m21=m11; m22=m12; m23=m13;
        m10=H0;  m11=H1;  m12=H2;  m13=H3;
        e3=e2r;  e2r=e1r; e1r=H4;
    };

#pragma unroll
    for (int i = 0; i < NIT; i += 2) {
        step(i,     eA, oA);
        step(i + 1, eB, oB);
    }
}

extern "C" void kernel_launch(void* const* d_in, const int* in_sizes, int n_in,
                              void* d_out, int out_size, void* d_ws, size_t ws_size,
                              hipStream_t stream)
{
    const float* x  = (const float*)d_in[0];
    const float* k4 = (const float*)d_in[1];
    float* out      = (float*)d_out;

    dim3 grid(NBC, NSTRIP / 4, 1);   // 512 x 4 blocks, 4 independent waves each
    upsamp_fir_wave<<<grid, dim3(256), 0, stream>>>(x, k4, out);
}

// Round 6
// 290.574 us; speedup vs baseline: 1.0034x; 1.0034x over previous
//
#include <hip/hip_runtime.h>

// x: [16,128,128,128] fp32 ; pixel_shuffle(2) -> [16,32,256,256]
// 4x4 separable FIR (outer([1,3,3,1])/64), pad=2 -> out [16,32,257,257]
//
// R7: barrier-free, LDS-free, one wave = one 17-row output strip; lane owns
// 4 consecutive cols. Occ 79%, but stores at 16B lane stride (OW=257 kills
// provable 16B alignment -> 4 scalar dword stores) partially dirtied
// sectors: ECC RMW amplified WRITE 133->236MB and added +48MB FETCH.
// Kernel was HBM-bound on amplified traffic (2.87 TB/s on 361MB = 126us).
//
// R8: keep R7 compute; fix stores via wave-private LDS transpose.
//   compute o[4] -> ds_write_b128 (lane-> trow[4*lane], 2-way alias = free)
//   -> lgkmcnt (compiler, intra-wave, NO barrier) -> read trow[lane+64q]
//   (2-way, free) -> 4 store instrs, each 256B lane-contiguous = full
//   sectors, no RMW. Edge col 256: lane63 scalar store, contiguous with
//   next row of the same strip (strip rows are contiguous in memory).
//   LDS 4KB/block (4 waves x 2x256 f32... actually 4x256) -> 8 blocks/CU
//   unaffected. Traffic back to ~203MB => 55-70us at demonstrated BW.
// Invariant: VGPR <= 64 (8 waves/SIMD); stores must be lane-consecutive
// (ECC partial-sector RMW costs ~1.8x write + read-back otherwise).
constexpr int Hn = 128;
constexpr int Wn = 128;
constexpr int SH = 2 * Hn;   // 256 shuffled rows
constexpr int OH = SH + 1;   // 257
constexpr int OW = 257;
constexpr int HW = Hn * Wn;  // input plane stride
constexpr int TY = 17;       // output rows per wave
constexpr int NSTRIP = 16;   // 16*17 = 272 >= 257
constexpr int NBC = 16 * 32; // 512 (b,c) planes
constexpr int NIT = TY + 3;  // 20 staged shuffled rows per strip

__global__ __launch_bounds__(256, 8) void upsamp_fir_wavet(
    const float* __restrict__ x,
    const float* __restrict__ k4,
    float* __restrict__ out)
{
    const int tix   = threadIdx.x;
    const int lane  = tix & 63;
    const int wid   = tix >> 6;
    const int bc    = blockIdx.x;
    const int strip = blockIdx.y * 4 + wid;
    const int oh0   = strip * TY;

    const float* xp = x + (size_t)bc * 4 * HW;

    // Per-wave transpose buffer (no cross-wave sharing -> no barriers).
    __shared__ __align__(16) float tbuf[4][256];
    float* const trow = tbuf[wid];

    // Separable taps (flipped for true convolution), exact for this kernel.
    float fh[4], fv[4];
#pragma unroll
    for (int j = 0; j < 4; ++j) fh[j] = k4[j] + k4[4+j] + k4[8+j] + k4[12+j];
#pragma unroll
    for (int i = 0; i < 4; ++i) fv[i] = k4[4*i] + k4[4*i+1] + k4[4*i+2] + k4[4*i+3];
    const float h0 = fh[3], h1 = fh[2], h2 = fh[1], h3 = fh[0];
    const float g0 = fv[3], g1 = fv[2], g2 = fv[1], g3 = fv[0];

    const bool l0  = (lane == 0);
    const bool l63 = (lane == 63);
    const int  colOff = 2 * lane;              // input col of E2.x / O2.x

    // Load shuffled row s: E pair (even out-cols 4m,4m+2 = input cols
    // 2m,2m+1 of plane 2*(s&1)) and O pair (odd cols, plane 2*(s&1)+1).
    auto loadrow = [&](int s, float2& e2, float2& o2) {
        if ((unsigned)s >= (unsigned)SH) {
            e2 = make_float2(0.f, 0.f); o2 = e2; return;
        }
        const float* be = xp + (size_t)((s & 1) * 2) * HW
                             + (size_t)(s >> 1) * Wn + colOff;
        e2 = *(const float2*)be;
        o2 = *(const float2*)(be + HW);
    };

    float2 eA, oA, eB, oB;
    loadrow(oh0 - 2, eA, oA);
    loadrow(oh0 - 1, eB, oB);

    // Rolling horizontal results for the 4 owned cols + edge col 256.
    float m30=0,m31=0,m32=0,m33=0;   // H(s-3)
    float m20=0,m21=0,m22=0,m23=0;   // H(s-2)
    float m10=0,m11=0,m12=0,m13=0;   // H(s-1)
    float e3=0, e2r=0, e1r=0;        // edge col rolling

    float* const obase = out + (size_t)bc * OH * OW;

    auto step = [&](int i, float2& E2, float2& O2) {
        const int s = oh0 - 2 + i;
        const float Ex = E2.x, Ey = E2.y, Ox = O2.x, Oy = O2.y;
        // Cross-lane neighbors (wave edge = global zero-pad).
        float Em1 = __shfl_up(Ey, 1);   Em1 = l0  ? 0.f : Em1;  // E[2m-1]
        float Om1 = __shfl_up(Oy, 1);   Om1 = l0  ? 0.f : Om1;  // O[2m-1]
        float Ep1 = __shfl_down(Ex, 1); Ep1 = l63 ? 0.f : Ep1;  // E[2m+2]
        // Horizontal FIR, out cols 4m..4m+3 (+ col 256 in lane 63).
        const float H0 = h0*Em1 + h1*Om1 + h2*Ex + h3*Ox;
        const float H1 = h0*Om1 + h1*Ex  + h2*Ox + h3*Ey;
        const float H2 = h0*Ex  + h1*Ox  + h2*Ey + h3*Oy;
        const float H3 = h0*Ox  + h1*Ey  + h2*Oy + h3*Ep1;
        const float H4 = h0*Ey  + h1*Oy;                    // col 256
        // Prefetch row s+2 into this buffer (consumed 2 steps later);
        // vmcnt is independent of the lgkm transpose waits below.
        if (i + 2 < NIT) loadrow(s + 2, E2, O2);
        // Emit output row oh = s-1 (needs H rows s-3..s).
        if (i >= 3) {
            const int oh = oh0 + i - 3;
            if (oh < OH) {
                float4 o4;
                o4.x = g0*m30 + g1*m20 + g2*m10 + g3*H0;
                o4.y = g0*m31 + g1*m21 + g2*m11 + g3*H1;
                o4.z = g0*m32 + g1*m22 + g2*m12 + g3*H2;
                o4.w = g0*m33 + g1*m23 + g2*m13 + g3*H3;
                const float oe = g0*e3 + g1*e2r + g2*e1r + g3*H4; // col 256
                // Wave-private transpose: strided-per-lane -> lane-contiguous.
                *(float4*)(trow + 4 * lane) = o4;      // ds_write_b128
                const float s0 = trow[lane];           // compiler lgkmcnt
                const float s1 = trow[lane + 64];
                const float s2 = trow[lane + 128];
                const float s3 = trow[lane + 192];
                float* pr = obase + (size_t)oh * OW;
                pr[lane]       = s0;   // 256B contiguous per store instr
                pr[lane + 64]  = s1;
                pr[lane + 128] = s2;
                pr[lane + 192] = s3;
                if (l63) pr[256] = oe;
            }
        }
        // Roll.
        m30=m20; m31=m21; m32=m22; m33=m23;
        m20=m10; m21=m11; m22=m12; m23=m13;
        m10=H0;  m11=H1;  m12=H2;  m13=H3;
        e3=e2r;  e2r=e1r; e1r=H4;
    };

#pragma unroll
    for (int i = 0; i < NIT; i += 2) {
        step(i,     eA, oA);
        step(i + 1, eB, oB);
    }
}

extern "C" void kernel_launch(void* const* d_in, const int* in_sizes, int n_in,
                              void* d_out, int out_size, void* d_ws, size_t ws_size,
                              hipStream_t stream)
{
    const float* x  = (const float*)d_in[0];
    const float* k4 = (const float*)d_in[1];
    float* out      = (float*)d_out;

    dim3 grid(NBC, NSTRIP / 4, 1);   // 512 x 4 blocks, 4 independent waves each
    upsamp_fir_wavet<<<grid, dim3(256), 0, stream>>>(x, k4, out);
}